// Round 1
// baseline (200.408 us; speedup 1.0000x reference)
//
#include <hip/hip_runtime.h>
#include <hip/hip_bf16.h>
#include <stdint.h>

typedef __attribute__((ext_vector_type(8))) short short8;   // 8 bf16 (4 VGPRs) MFMA A/B frag
typedef __attribute__((ext_vector_type(4))) float f32x4;    // MFMA C/D frag

__device__ __forceinline__ float softplus_f(float x) {
    // log1p(exp(x)), numerically stable
    return (x > 0.f) ? (x + log1pf(expf(-x))) : log1pf(expf(x));
}

// mode 0: plain cast; mode 1: column-monotone (cols 0..3 -> +softplus, 4..7 -> -softplus, rest raw, 256 cols);
// mode 2: softplus everywhere
__global__ void xform_kernel(const float* __restrict__ src, __hip_bfloat16* __restrict__ dst,
                             int n4, int mode) {
    int i = blockIdx.x * blockDim.x + threadIdx.x;
    if (i >= n4) return;
    float4 v = reinterpret_cast<const float4*>(src)[i];
    float r[4] = {v.x, v.y, v.z, v.w};
    int base = i << 2;
#pragma unroll
    for (int j = 0; j < 4; ++j) {
        float x = r[j];
        float y = x;
        if (mode == 2) {
            y = softplus_f(x);
        } else if (mode == 1) {
            int col = (base + j) & 255;
            if (col < 8) {
                float s = softplus_f(x);
                y = (col < 4) ? s : -s;
            }
        }
        dst[base + j] = __float2bfloat16(y);
    }
}

// One K-segment of the fused GEMM: acc += A[brow:brow+128, k] * B[bcol:bcol+128, k]^T
// A,B are bf16 row-major [rows][ld]; LDS tiles are linear [128][32] (global_load_lds needs linear dest).
__device__ __forceinline__ void gemm_seg(const short* __restrict__ AG, int lda,
                                         const short* __restrict__ BG, int ldb,
                                         int K, int brow, int bcol,
                                         short* As, short* Bs,
                                         f32x4 (&acc)[4][4],
                                         int t, int wr, int wcol, int l15, int l4)
{
    for (int k0 = 0; k0 < K; k0 += 32) {
        // ---- stage A and B tiles (128x32 bf16 = 8KB each) via direct global->LDS, 16B/lane ----
#pragma unroll
        for (int it = 0; it < 2; ++it) {
            int c = it * 256 + t;               // chunk id 0..511, 16B each
            int row = c >> 2;                   // 4 chunks per 32-elem row
            int kp = (c & 3) << 3;
            const short* srcA = AG + (size_t)(brow + row) * lda + k0 + kp;
            __builtin_amdgcn_global_load_lds((const __attribute__((address_space(1))) void*)srcA,
                                             (__attribute__((address_space(3))) void*)(As + c * 8),
                                             16, 0, 0);
            const short* srcB = BG + (size_t)(bcol + row) * ldb + k0 + kp;
            __builtin_amdgcn_global_load_lds((const __attribute__((address_space(1))) void*)srcB,
                                             (__attribute__((address_space(3))) void*)(Bs + c * 8),
                                             16, 0, 0);
        }
        __syncthreads();   // drains vmcnt(0) before barrier -> LDS tiles complete

        short8 a[4], b[4];
#pragma unroll
        for (int m = 0; m < 4; ++m)
            a[m] = *(const short8*)(As + (wr * 64 + m * 16 + l15) * 32 + l4 * 8);
#pragma unroll
        for (int n = 0; n < 4; ++n)
            b[n] = *(const short8*)(Bs + (wcol * 64 + n * 16 + l15) * 32 + l4 * 8);
#pragma unroll
        for (int m = 0; m < 4; ++m)
#pragma unroll
            for (int n = 0; n < 4; ++n)
                acc[m][n] = __builtin_amdgcn_mfma_f32_16x16x32_bf16(a[m], b[n], acc[m][n], 0, 0, 0);
        __syncthreads();   // protect LDS from next iteration's staging
    }
}

// Fused ICNN layer: z_out = relu(xc@Wc^T + bc + xf@Wu^T + bu + [z@U^T] + relu(xf@Wut^T + but))
// M=8192, N=1024, tile 128x128, 4 waves (2x2), 4x4 16x16 fragments per wave.
template<bool HAS_U, bool WRITE_F32>
__global__ __launch_bounds__(256, 2)
void icnn_layer_kernel(const short* __restrict__ xc, const short* __restrict__ xf,
                       const short* __restrict__ zin,
                       const short* __restrict__ Wc, const short* __restrict__ Wu,
                       const short* __restrict__ Wut, const short* __restrict__ U,
                       const float* __restrict__ bc, const float* __restrict__ bu,
                       const float* __restrict__ but,
                       __hip_bfloat16* __restrict__ zout, float* __restrict__ fout)
{
    __shared__ short As[128 * 32];
    __shared__ short Bs[128 * 32];
    const int t = threadIdx.x;
    const int lane = t & 63;
    const int wid = t >> 6;
    const int wr = wid >> 1, wcol = wid & 1;
    const int l15 = lane & 15, l4 = lane >> 4;
    const int brow = blockIdx.x * 128;
    const int bcol = blockIdx.y * 128;

    f32x4 acc[4][4];
    const f32x4 zero4 = {0.f, 0.f, 0.f, 0.f};
#pragma unroll
    for (int m = 0; m < 4; ++m)
#pragma unroll
        for (int n = 0; n < 4; ++n) acc[m][n] = zero4;

    // ---- u-path: acc = xf @ Wut^T ----
    gemm_seg(xf, 256, Wut, 256, 256, brow, bcol, As, Bs, acc, t, wr, wcol, l15, l4);

    // u = relu(u + but); becomes the initial value of agg (MFMA keeps accumulating on top)
#pragma unroll
    for (int n = 0; n < 4; ++n) {
        float bt = but[bcol + wcol * 64 + n * 16 + l15];
#pragma unroll
        for (int m = 0; m < 4; ++m)
#pragma unroll
            for (int v = 0; v < 4; ++v)
                acc[m][n][v] = fmaxf(acc[m][n][v] + bt, 0.f);
    }

    // ---- convex path, free path, recurrent path ----
    gemm_seg(xc, 256, Wc, 256, 256, brow, bcol, As, Bs, acc, t, wr, wcol, l15, l4);
    gemm_seg(xf, 256, Wu, 256, 256, brow, bcol, As, Bs, acc, t, wr, wcol, l15, l4);
    if constexpr (HAS_U) {
        gemm_seg(zin, 1024, U, 1024, 1024, brow, bcol, As, Bs, acc, t, wr, wcol, l15, l4);
    }

    // ---- epilogue: + (bc + bu), relu, store ----
#pragma unroll
    for (int n = 0; n < 4; ++n) {
        int col = bcol + wcol * 64 + n * 16 + l15;
        float bb = bc[col] + bu[col];
#pragma unroll
        for (int m = 0; m < 4; ++m) {
            int row = brow + wr * 64 + m * 16 + l4 * 4;
#pragma unroll
            for (int v = 0; v < 4; ++v) {
                float val = fmaxf(acc[m][n][v] + bb, 0.f);
                if constexpr (WRITE_F32) {
                    fout[(size_t)(row + v) * 1024 + col] = val;
                } else {
                    zout[(size_t)(row + v) * 1024 + col] = __float2bfloat16(val);
                }
            }
        }
    }
}

extern "C" void kernel_launch(void* const* d_in, const int* in_sizes, int n_in,
                              void* d_out, int out_size, void* d_ws, size_t ws_size,
                              hipStream_t stream)
{
    const float* xc    = (const float*)d_in[0];
    const float* xf    = (const float*)d_in[1];
    const float* Wc_w  = (const float*)d_in[2];
    const float* Wc_b  = (const float*)d_in[3];
    const float* Wu_w  = (const float*)d_in[4];
    const float* Wu_b  = (const float*)d_in[5];
    const float* Wut_w = (const float*)d_in[6];
    const float* Wut_b = (const float*)d_in[7];
    const float* raw_U = (const float*)d_in[8];

    // workspace layout (bf16 buffers), ~36 MB total
    short* p = (short*)d_ws;
    short* xc_bf  = p; p += 8192 * 256;
    short* xf_bf  = p; p += 8192 * 256;
    short* Wc_bf  = p; p += 4 * 1024 * 256;
    short* Wu_bf  = p; p += 4 * 1024 * 256;
    short* Wut_bf = p; p += 4 * 1024 * 256;
    short* U_bf   = p; p += 3 * 1024 * 1024;
    short* z_a    = p; p += 8192 * 1024;
    // z_b lives in d_out (bf16 scratch, 16MB of the 33.5MB fp32 output buffer);
    // layer 3 fully overwrites d_out with the final fp32 result.
    short* z_b = (short*)d_out;

    dim3 tb(256);
    xform_kernel<<<dim3(2048), tb, 0, stream>>>(xc,    (__hip_bfloat16*)xc_bf,  8192 * 256 / 4, 0);
    xform_kernel<<<dim3(2048), tb, 0, stream>>>(xf,    (__hip_bfloat16*)xf_bf,  8192 * 256 / 4, 0);
    xform_kernel<<<dim3(1024), tb, 0, stream>>>(Wc_w,  (__hip_bfloat16*)Wc_bf,  4 * 1024 * 256 / 4, 1);
    xform_kernel<<<dim3(1024), tb, 0, stream>>>(Wu_w,  (__hip_bfloat16*)Wu_bf,  4 * 1024 * 256 / 4, 1);
    xform_kernel<<<dim3(1024), tb, 0, stream>>>(Wut_w, (__hip_bfloat16*)Wut_bf, 4 * 1024 * 256 / 4, 1);
    xform_kernel<<<dim3(3072), tb, 0, stream>>>(raw_U, (__hip_bfloat16*)U_bf,   3 * 1024 * 1024 / 4, 2);

    dim3 grid(8192 / 128, 1024 / 128);   // 64 x 8
    const int WS = 1024 * 256;           // per-layer weight stride (elements)
    const int US = 1024 * 1024;

    // layer 0 (no recurrence) -> z_a
    icnn_layer_kernel<false, false><<<grid, tb, 0, stream>>>(
        xc_bf, xf_bf, nullptr, Wc_bf, Wu_bf, Wut_bf, nullptr,
        Wc_b, Wu_b, Wut_b, (__hip_bfloat16*)z_a, nullptr);
    // layer 1 -> z_b (in d_out)
    icnn_layer_kernel<true, false><<<grid, tb, 0, stream>>>(
        xc_bf, xf_bf, z_a, Wc_bf + WS, Wu_bf + WS, Wut_bf + WS, U_bf,
        Wc_b + 1024, Wu_b + 1024, Wut_b + 1024, (__hip_bfloat16*)z_b, nullptr);
    // layer 2 -> z_a
    icnn_layer_kernel<true, false><<<grid, tb, 0, stream>>>(
        xc_bf, xf_bf, z_b, Wc_bf + 2 * WS, Wu_bf + 2 * WS, Wut_bf + 2 * WS, U_bf + US,
        Wc_b + 2048, Wu_b + 2048, Wut_b + 2048, (__hip_bfloat16*)z_a, nullptr);
    // layer 3 -> fp32 d_out
    icnn_layer_kernel<true, true><<<grid, tb, 0, stream>>>(
        xc_bf, xf_bf, z_a, Wc_bf + 3 * WS, Wu_bf + 3 * WS, Wut_bf + 3 * WS, U_bf + 2 * US,
        Wc_b + 3072, Wu_b + 3072, Wut_b + 3072, nullptr, (float*)d_out);
}

// Round 2
// 175.857 us; speedup vs baseline: 1.1396x; 1.1396x over previous
//
#include <hip/hip_runtime.h>
#include <hip/hip_bf16.h>
#include <stdint.h>

typedef __attribute__((ext_vector_type(8))) short short8;   // 8 bf16 (4 VGPRs) MFMA A/B frag
typedef __attribute__((ext_vector_type(4))) float f32x4;    // MFMA C/D frag

__device__ __forceinline__ float softplus_f(float x) {
    return (x > 0.f) ? (x + log1pf(expf(-x))) : log1pf(expf(x));
}

// mode 0: plain cast; mode 1: column-monotone (cols 0..3 -> +softplus, 4..7 -> -softplus, rest raw, 256 cols);
// mode 2: softplus everywhere
__global__ void xform_kernel(const float* __restrict__ src, __hip_bfloat16* __restrict__ dst,
                             int n4, int mode) {
    int i = blockIdx.x * blockDim.x + threadIdx.x;
    if (i >= n4) return;
    float4 v = reinterpret_cast<const float4*>(src)[i];
    float r[4] = {v.x, v.y, v.z, v.w};
    int base = i << 2;
#pragma unroll
    for (int j = 0; j < 4; ++j) {
        float x = r[j];
        float y = x;
        if (mode == 2) {
            y = softplus_f(x);
        } else if (mode == 1) {
            int col = (base + j) & 255;
            if (col < 8) {
                float s = softplus_f(x);
                y = (col < 4) ? s : -s;
            }
        }
        dst[base + j] = __float2bfloat16(y);
    }
}

#define GLOAD16(src, dst)                                                                  \
    __builtin_amdgcn_global_load_lds((const __attribute__((address_space(1))) void*)(src), \
                                     (__attribute__((address_space(3))) void*)(dst), 16, 0, 0)

// Fused ICNN layer, 128x128 tile, 8 waves (2x4), BK=64, double-buffered LDS,
// single barrier per K-step (T3 minimum 2-phase), T2 XOR-swizzle via pre-swizzled source.
// Step map: 0-3 u-path (xf@Wut^T, relu'd at step 3), 4-7 xc@Wc^T, 8-11 xf@Wu^T, 12-27 z@U^T.
template<bool HAS_U, bool WRITE_F32>
__global__ __launch_bounds__(512, 4)
void icnn_layer_kernel(const short* __restrict__ xc, const short* __restrict__ xf,
                       const short* __restrict__ zin,
                       const short* __restrict__ Wc, const short* __restrict__ Wu,
                       const short* __restrict__ Wut, const short* __restrict__ U,
                       const float* __restrict__ bc, const float* __restrict__ bu,
                       const float* __restrict__ but,
                       __hip_bfloat16* __restrict__ zout, float* __restrict__ fout)
{
    __shared__ short As[2][128 * 64];   // 16KB per buffer
    __shared__ short Bs[2][128 * 64];   // total 64KB
    const int t = threadIdx.x;          // 0..511
    const int lane = t & 63;
    const int wid = t >> 6;             // 0..7
    const int wr = wid >> 2;            // 0..1 (64-row slice)
    const int wc = wid & 3;             // 0..3 (32-col slice)
    const int l15 = lane & 15, l4 = lane >> 4;
    const int swz = l15 & 7;            // row&7 for all fragment rows this lane touches
    const int brow = blockIdx.x * 128;
    const int bcol = blockIdx.y * 128;

    constexpr int NSTEP = HAS_U ? 28 : 12;

    f32x4 acc[4][2];
#pragma unroll
    for (int m = 0; m < 4; ++m)
#pragma unroll
        for (int n = 0; n < 2; ++n) acc[m][n] = (f32x4){0.f, 0.f, 0.f, 0.f};

    // hoist u-path bias
    float bt[2];
#pragma unroll
    for (int n = 0; n < 2; ++n) bt[n] = but[bcol + wc * 32 + n * 16 + l15];

    // resolve operand pointers for step s
    auto seg = [&](int s, const short*& A, int& lda, const short*& B, int& ldb, int& k0) {
        if (s < 4)       { A = xf;  lda = 256;  B = Wut; ldb = 256;  k0 = s * 64; }
        else if (s < 8)  { A = xc;  lda = 256;  B = Wc;  ldb = 256;  k0 = (s - 4) * 64; }
        else if (s < 12) { A = xf;  lda = 256;  B = Wu;  ldb = 256;  k0 = (s - 8) * 64; }
        else             { A = zin; lda = 1024; B = U;   ldb = 1024; k0 = (s - 12) * 64; }
    };

    // stage tile for step s into buffer sel; LDS dest linear, source column-chunk XOR-swizzled
    auto stage = [&](int sel, int s) {
        const short *A, *B; int lda, ldb, k0;
        seg(s, A, lda, B, ldb, k0);
#pragma unroll
        for (int it = 0; it < 2; ++it) {
            int c = it * 512 + t;            // chunk 0..1023, 16B each; 8 chunks per 64-elem row
            int row = c >> 3;
            int js = (c & 7) ^ (row & 7);    // inverse swizzle on source
            GLOAD16(A + (size_t)(brow + row) * lda + k0 + js * 8, &As[sel][c * 8]);
            GLOAD16(B + (size_t)(bcol + row) * ldb + k0 + js * 8, &Bs[sel][c * 8]);
        }
    };

    auto compute = [&](int sel) {
        const short* Asel = &As[sel][0];
        const short* Bsel = &Bs[sel][0];
#pragma unroll
        for (int kk = 0; kk < 2; ++kk) {
            int joff = ((kk * 4 + l4) ^ swz) << 3;   // swizzled column offset (shorts)
            short8 a[4], b[2];
#pragma unroll
            for (int m = 0; m < 4; ++m) {
                int row = wr * 64 + m * 16 + l15;
                a[m] = *(const short8*)&Asel[(row << 6) + joff];
            }
#pragma unroll
            for (int n = 0; n < 2; ++n) {
                int row = wc * 32 + n * 16 + l15;
                b[n] = *(const short8*)&Bsel[(row << 6) + joff];
            }
#pragma unroll
            for (int m = 0; m < 4; ++m)
#pragma unroll
                for (int n = 0; n < 2; ++n)
                    acc[m][n] = __builtin_amdgcn_mfma_f32_16x16x32_bf16(a[m], b[n], acc[m][n], 0, 0, 0);
        }
    };

    // ---- pipelined K-loop: one barrier per step ----
    stage(0, 0);
    __syncthreads();
    int cur = 0;
    for (int s = 0; s < NSTEP; ++s) {
        if (s + 1 < NSTEP) stage(cur ^ 1, s + 1);
        compute(cur);
        if (s == 3) {
            // u = relu(xf@Wut^T + but); MFMA keeps accumulating the other paths on top
#pragma unroll
            for (int n = 0; n < 2; ++n)
#pragma unroll
                for (int m = 0; m < 4; ++m)
#pragma unroll
                    for (int v = 0; v < 4; ++v)
                        acc[m][n][v] = fmaxf(acc[m][n][v] + bt[n], 0.f);
        }
        __syncthreads();   // drains vmcnt(0): next buffer staged; also protects cur buffer reuse
        cur ^= 1;
    }

    // ---- epilogue: + (bc + bu), relu, store ----
#pragma unroll
    for (int n = 0; n < 2; ++n) {
        int col = bcol + wc * 32 + n * 16 + l15;
        float bb = bc[col] + bu[col];
#pragma unroll
        for (int m = 0; m < 4; ++m) {
            int row = brow + wr * 64 + m * 16 + l4 * 4;
#pragma unroll
            for (int v = 0; v < 4; ++v) {
                float val = fmaxf(acc[m][n][v] + bb, 0.f);
                if constexpr (WRITE_F32) {
                    fout[(size_t)(row + v) * 1024 + col] = val;
                } else {
                    zout[(size_t)(row + v) * 1024 + col] = __float2bfloat16(val);
                }
            }
        }
    }
}

extern "C" void kernel_launch(void* const* d_in, const int* in_sizes, int n_in,
                              void* d_out, int out_size, void* d_ws, size_t ws_size,
                              hipStream_t stream)
{
    const float* xc    = (const float*)d_in[0];
    const float* xf    = (const float*)d_in[1];
    const float* Wc_w  = (const float*)d_in[2];
    const float* Wc_b  = (const float*)d_in[3];
    const float* Wu_w  = (const float*)d_in[4];
    const float* Wu_b  = (const float*)d_in[5];
    const float* Wut_w = (const float*)d_in[6];
    const float* Wut_b = (const float*)d_in[7];
    const float* raw_U = (const float*)d_in[8];

    // workspace layout (bf16 buffers), ~36 MB total
    short* p = (short*)d_ws;
    short* xc_bf  = p; p += 8192 * 256;
    short* xf_bf  = p; p += 8192 * 256;
    short* Wc_bf  = p; p += 4 * 1024 * 256;
    short* Wu_bf  = p; p += 4 * 1024 * 256;
    short* Wut_bf = p; p += 4 * 1024 * 256;
    short* U_bf   = p; p += 3 * 1024 * 1024;
    short* z_a    = p; p += 8192 * 1024;
    // z_b lives in d_out (bf16 scratch); layer 3 fully overwrites d_out with fp32 result.
    short* z_b = (short*)d_out;

    dim3 tb256(256);
    xform_kernel<<<dim3(2048), tb256, 0, stream>>>(xc,    (__hip_bfloat16*)xc_bf,  8192 * 256 / 4, 0);
    xform_kernel<<<dim3(2048), tb256, 0, stream>>>(xf,    (__hip_bfloat16*)xf_bf,  8192 * 256 / 4, 0);
    xform_kernel<<<dim3(1024), tb256, 0, stream>>>(Wc_w,  (__hip_bfloat16*)Wc_bf,  4 * 1024 * 256 / 4, 1);
    xform_kernel<<<dim3(1024), tb256, 0, stream>>>(Wu_w,  (__hip_bfloat16*)Wu_bf,  4 * 1024 * 256 / 4, 1);
    xform_kernel<<<dim3(1024), tb256, 0, stream>>>(Wut_w, (__hip_bfloat16*)Wut_bf, 4 * 1024 * 256 / 4, 1);
    xform_kernel<<<dim3(3072), tb256, 0, stream>>>(raw_U, (__hip_bfloat16*)U_bf,   3 * 1024 * 1024 / 4, 2);

    dim3 tb(512);
    dim3 grid(8192 / 128, 1024 / 128);   // 64 x 8 = 512 blocks = 2/CU
    const int WS = 1024 * 256;
    const int US = 1024 * 1024;

    // layer 0 (no recurrence) -> z_a
    icnn_layer_kernel<false, false><<<grid, tb, 0, stream>>>(
        xc_bf, xf_bf, nullptr, Wc_bf, Wu_bf, Wut_bf, nullptr,
        Wc_b, Wu_b, Wut_b, (__hip_bfloat16*)z_a, nullptr);
    // layer 1 -> z_b (in d_out)
    icnn_layer_kernel<true, false><<<grid, tb, 0, stream>>>(
        xc_bf, xf_bf, z_a, Wc_bf + WS, Wu_bf + WS, Wut_bf + WS, U_bf,
        Wc_b + 1024, Wu_b + 1024, Wut_b + 1024, (__hip_bfloat16*)z_b, nullptr);
    // layer 2 -> z_a
    icnn_layer_kernel<true, false><<<grid, tb, 0, stream>>>(
        xc_bf, xf_bf, z_b, Wc_bf + 2 * WS, Wu_bf + 2 * WS, Wut_bf + 2 * WS, U_bf + US,
        Wc_b + 2048, Wu_b + 2048, Wut_b + 2048, (__hip_bfloat16*)z_a, nullptr);
    // layer 3 -> fp32 d_out
    icnn_layer_kernel<true, true><<<grid, tb, 0, stream>>>(
        xc_bf, xf_bf, z_a, Wc_bf + 3 * WS, Wu_bf + 3 * WS, Wut_bf + 3 * WS, U_bf + 2 * US,
        Wc_b + 3072, Wu_b + 3072, Wut_b + 3072, nullptr, (float*)d_out);
}